// Round 3
// baseline (207.838 us; speedup 1.0000x reference)
//
#include <hip/hip_runtime.h>
#include <hip/hip_cooperative_groups.h>

namespace cg = cooperative_groups;

// MS_SSA_Conv: spiking self-attention, T=4, C=512, N=196 (14x14), fp32.
// All matmul inputs are spikes {0,1} (~3-4% density) -> sparse masked
// column-sums of W. to_heads is a pure relabeling (c = nh*64 + hd).
//
// R3: single cooperative kernel (196 blocks x 512 thr), two grid.sync():
//   phase 0: transpose W -> Wt in ws (distributed), zero kvsum
//   phase 1: LIF(x) -> sparse qkv accumulate -> BN+LIF; sq kept IN REGISTERS
//            (same thread owns (c,n) in both phases); kvsum += sk&sv atomics
//   phase 2: talking-heads LIF(kvsum) & sq -> sparse proj -> epilogue + identity
// Tests whether R1/R2's ~126 us was per-dispatch overhead (3 dispatches ->
// 1) or harness-floor (poison fills in timed window).

#define TT 4
#define CC 512
#define NN 196
#define BEPS 1e-5f

// ws layout in floats
#define WQT_OFF 0
#define WKT_OFF (512 * 512)
#define WVT_OFF (2 * 512 * 512)
#define WPT_OFF (3 * 512 * 512)
#define KV_OFF  (4 * 512 * 512)   // T*C floats

__device__ __forceinline__ int bn_lif4(const float* acc, float sc, float of) {
    float v = 0.0f;
    int bits = 0;
#pragma unroll
    for (int t = 0; t < TT; ++t) {
        float y = acc[t] * sc + of;
        v = v + (y - v) * 0.5f;            // v += (y - v)/tau, tau=2
        if (v >= 1.0f) { bits |= (1 << t); v = 0.0f; }
    }
    return bits;
}

// ballot-compact: append set lanes' channel ids to actrow[]
__device__ __forceinline__ void compact_append(int flag, int ch, int lane,
                                               unsigned short* actrow, int* cntp)
{
    unsigned long long m = __ballot(flag);
    int base = 0;
    if (lane == 0 && m) base = atomicAdd(cntp, __popcll(m));
    base = __shfl(base, 0);
    if (flag) actrow[base + __popcll(m & ((1ull << lane) - 1ull))] = (unsigned short)ch;
}

__global__ __launch_bounds__(512) void fused_ssa(
    const float* __restrict__ x,
    const float* __restrict__ qw, const float* __restrict__ kw,
    const float* __restrict__ vw, const float* __restrict__ pw,
    const float* __restrict__ pbias,
    const float* __restrict__ qg, const float* __restrict__ qb,
    const float* __restrict__ qm, const float* __restrict__ qv,
    const float* __restrict__ kg, const float* __restrict__ kb,
    const float* __restrict__ km, const float* __restrict__ kvv,
    const float* __restrict__ vg, const float* __restrict__ vb,
    const float* __restrict__ vm, const float* __restrict__ vvv,
    const float* __restrict__ pg, const float* __restrict__ pb,
    const float* __restrict__ pm, const float* __restrict__ pv,
    float* __restrict__ ws, float* __restrict__ out)
{
    cg::grid_group grid = cg::this_grid();
    const int b    = blockIdx.x;     // 0..195, also n
    const int tid  = threadIdx.x;    // 0..511, owns channel/output tid
    const int lane = tid & 63;

    __shared__ float tile[64][65];               // phase 0 only
    __shared__ unsigned short act[TT][CC];
    __shared__ int cnt[TT];

    // ---------- Phase 0: transpose 4 W matrices into ws; zero kvsum ----------
    {
        const int lr = tid >> 6;   // 0..7 (wave id)
        const int lc = tid & 63;
        for (int job = b; job < 256; job += 196) {   // 4 mats x 64 tiles of 64x64
            const int mat = job >> 6;
            const int t6  = job & 63;
            const int to  = (t6 >> 3) * 64;
            const int tc  = (t6 & 7) * 64;
            const float* W = (mat == 0) ? qw : (mat == 1) ? kw : (mat == 2) ? vw : pw;
            float* Wt = ws + (size_t)mat * (512 * 512);
#pragma unroll
            for (int i = 0; i < 8; ++i) {
                const int r = i * 8 + lr;
                tile[r][lc] = W[(size_t)(to + r) * 512 + (tc + lc)];  // coalesced
            }
            __syncthreads();
#pragma unroll
            for (int i = 0; i < 8; ++i) {
                const int r = i * 8 + lr;  // c-local
                Wt[(size_t)(tc + r) * 512 + (to + lc)] = tile[lc][r]; // coalesced
            }
            __syncthreads();
        }
        if (b < TT) ws[KV_OFF + b * CC + tid] = 0.0f;  // zero kvsum (2048 floats)
    }
    grid.sync();

    // ---------- Phase 1: LIF(x), sparse qkv, BN+LIF, kvsum atomics ----------
    const int n = b;
    if (tid < TT) cnt[tid] = 0;

    int xf = 0;
    {
        float v = 0.0f;
        const float* xp = x + (size_t)tid * NN + n;
#pragma unroll
        for (int t = 0; t < TT; ++t) {
            const float a = xp[(size_t)t * CC * NN];
            v = v + (a - v) * 0.5f;
            if (v >= 1.0f) { xf |= (1 << t); v = 0.0f; }
        }
    }
    __syncthreads();
#pragma unroll
    for (int t = 0; t < TT; ++t)
        compact_append((xf >> t) & 1, tid, lane, act[t], &cnt[t]);
    __syncthreads();

    int ct[TT], mc = 0;
#pragma unroll
    for (int t = 0; t < TT; ++t) { ct[t] = cnt[t]; mc = max(mc, ct[t]); }

    float aq[TT] = {0,0,0,0}, ak[TT] = {0,0,0,0}, av[TT] = {0,0,0,0};
    {
        const float* Wqt = ws + WQT_OFF;
        const float* Wkt = ws + WKT_OFF;
        const float* Wvt = ws + WVT_OFF;
        for (int i = 0; i < mc; ++i) {
#pragma unroll
            for (int t = 0; t < TT; ++t) {
                if (i < ct[t]) {               // block-uniform, no divergence
                    const int c = act[t][i];   // LDS broadcast
                    aq[t] += Wqt[(size_t)c * CC + tid];
                    ak[t] += Wkt[(size_t)c * CC + tid];
                    av[t] += Wvt[(size_t)c * CC + tid];
                }
            }
        }
    }

    int sqb, skb, svb;
    {
        float sc = qg[tid] / sqrtf(qv[tid] + BEPS);
        sqb = bn_lif4(aq, sc, qb[tid] - qm[tid] * sc);
        sc = kg[tid] / sqrtf(kvv[tid] + BEPS);
        skb = bn_lif4(ak, sc, kb[tid] - km[tid] * sc);
        sc = vg[tid] / sqrtf(vvv[tid] + BEPS);
        svb = bn_lif4(av, sc, vb[tid] - vm[tid] * sc);
    }

    {
        float* kvsum = ws + KV_OFF;
        const int both = skb & svb;
#pragma unroll
        for (int t = 0; t < TT; ++t)
            if ((both >> t) & 1) atomicAdd(&kvsum[t * CC + tid], 1.0f);
    }
    grid.sync();

    // ---------- Phase 2: talking-heads LIF & sq -> sparse proj -> out ----------
    if (tid < TT) cnt[tid] = 0;

    int f = 0;
    {
        const float* kvsum = ws + KV_OFF;
        float v = 0.0f;
#pragma unroll
        for (int t = 0; t < TT; ++t) {
            const float a = kvsum[t * CC + tid];
            v = v + (a - v) * 0.5f;
            const int s = (v >= 0.5f);          // v_th = 0.5
            if (s) v = 0.0f;
            if (s && ((sqb >> t) & 1)) f |= (1 << t);   // attn spike for (c,n)
        }
    }
    __syncthreads();
#pragma unroll
    for (int t = 0; t < TT; ++t)
        compact_append((f >> t) & 1, tid, lane, act[t], &cnt[t]);
    __syncthreads();

    mc = 0;
#pragma unroll
    for (int t = 0; t < TT; ++t) { ct[t] = cnt[t]; mc = max(mc, ct[t]); }

    float a[TT] = {0,0,0,0};
    {
        const float* Wpt = ws + WPT_OFF;
        for (int i = 0; i < mc; ++i) {
#pragma unroll
            for (int t = 0; t < TT; ++t) {
                if (i < ct[t]) {
                    const int c = act[t][i];
                    a[t] += Wpt[(size_t)c * CC + tid];
                }
            }
        }
    }

    {
        const float sc = pg[tid] / sqrtf(pv[tid] + BEPS);
        const float of = pb[tid] - pm[tid] * sc;
        const float bi = pbias[tid];
#pragma unroll
        for (int t = 0; t < TT; ++t) {
            const size_t i0 = (size_t)(t * CC + tid) * NN + n;
            out[i0] = (a[t] + bi) * sc + of + x[i0];
        }
    }
}

extern "C" void kernel_launch(void* const* d_in, const int* in_sizes, int n_in,
                              void* d_out, int out_size, void* d_ws, size_t ws_size,
                              hipStream_t stream) {
    const float* x     = (const float*)d_in[0];
    const float* qw    = (const float*)d_in[1];
    const float* kw    = (const float*)d_in[2];
    const float* vw    = (const float*)d_in[3];
    const float* pw    = (const float*)d_in[4];
    const float* pbias = (const float*)d_in[5];
    const float* qg = (const float*)d_in[6],  *qb = (const float*)d_in[7];
    const float* qm = (const float*)d_in[8],  *qv = (const float*)d_in[9];
    const float* kg = (const float*)d_in[10], *kb = (const float*)d_in[11];
    const float* km = (const float*)d_in[12], *kv = (const float*)d_in[13];
    const float* vg = (const float*)d_in[14], *vb = (const float*)d_in[15];
    const float* vm = (const float*)d_in[16], *vv = (const float*)d_in[17];
    const float* pg = (const float*)d_in[18], *pb = (const float*)d_in[19];
    const float* pm = (const float*)d_in[20], *pv = (const float*)d_in[21];
    float* ws  = (float*)d_ws;
    float* out = (float*)d_out;

    void* args[] = {
        (void*)&x, (void*)&qw, (void*)&kw, (void*)&vw, (void*)&pw, (void*)&pbias,
        (void*)&qg, (void*)&qb, (void*)&qm, (void*)&qv,
        (void*)&kg, (void*)&kb, (void*)&km, (void*)&kv,
        (void*)&vg, (void*)&vb, (void*)&vm, (void*)&vv,
        (void*)&pg, (void*)&pb, (void*)&pm, (void*)&pv,
        (void*)&ws, (void*)&out
    };
    hipLaunchCooperativeKernel((const void*)fused_ssa, dim3(196), dim3(512),
                               args, 0, stream);
}

// Round 4
// 131.367 us; speedup vs baseline: 1.5821x; 1.5821x over previous
//
#include <hip/hip_runtime.h>

// MS_SSA_Conv: spiking self-attention, T=4, C=512, N=196 (14x14), fp32.
// All matmul inputs are spikes {0,1} (~3-4% density) -> sparse masked
// column-sums of W. to_heads is a pure relabeling (c = nh*64 + hd), so
// everything stays in [T,C,N] layout.
//
// R4: back to 3 plain dispatches (R3's cooperative fusion was -77 us).
// Bench window carries a ~120-130 us harness floor (~30 restore/poison
// dispatches incl. a 42 us 256 MiB ws-poison fill per iteration); the
// controllable slice is the 3 kernels (~5-15 us). This round: float2
// gathers (2 adjacent channels/thread -> half the wave-load instrs),
// byte-array sq instead of ballot bitmasks, 256-thread blocks.

#define TT 4
#define CC 512
#define NN 196
#define BEPS 1e-5f

// ws layout in floats
#define WQT_OFF 0
#define WKT_OFF (512 * 512)
#define WVT_OFF (2 * 512 * 512)
#define WVT3_OFF (3 * 512 * 512)
#define WPT_OFF (3 * 512 * 512)
#define KV_OFF  (4 * 512 * 512)             // T*C = 2048 floats
#define SQ_OFF  (4 * 512 * 512 + 2048)      // N*C bytes (uchar per (n,c))

__global__ __launch_bounds__(256) void k0_prep(
    const float* __restrict__ qw, const float* __restrict__ kw,
    const float* __restrict__ vw, const float* __restrict__ pw,
    float* __restrict__ ws)
{
    __shared__ float tile[64][65];  // +1 pad: conflict-free transpose
    const int b   = blockIdx.x;     // 256 blocks: 4 matrices x 8x8 tiles of 64x64
    const int mat = b >> 6;
    const int t6  = b & 63;
    const int to  = (t6 >> 3) * 64; // o-tile origin
    const int tc  = (t6 & 7) * 64;  // c-tile origin
    const float* W = (mat == 0) ? qw : (mat == 1) ? kw : (mat == 2) ? vw : pw;
    float* Wt = ws + (size_t)mat * (512 * 512);
    const int lr = threadIdx.x >> 6;   // 0..3
    const int lc = threadIdx.x & 63;
#pragma unroll
    for (int i = 0; i < 16; ++i) {
        int r = i * 4 + lr;
        tile[r][lc] = W[(size_t)(to + r) * 512 + (tc + lc)];   // coalesced read
    }
    __syncthreads();
#pragma unroll
    for (int i = 0; i < 16; ++i) {
        int r = i * 4 + lr;   // c-local
        Wt[(size_t)(tc + r) * 512 + (to + lc)] = tile[lc][r];  // coalesced write
    }
    if (b == 0) {
        for (int i = threadIdx.x; i < TT * CC; i += 256) ws[KV_OFF + i] = 0.0f;
    }
}

__device__ __forceinline__ int bn_lif4(const float* acc, float sc, float of) {
    float v = 0.0f;
    int bits = 0;
#pragma unroll
    for (int t = 0; t < TT; ++t) {
        float y = acc[t] * sc + of;
        v = v + (y - v) * 0.5f;            // v += (y - v)/tau, tau=2
        if (v >= 1.0f) { bits |= (1 << t); v = 0.0f; }
    }
    return bits;
}

// ballot-compact: append set lanes' channel ids to actrow[]
__device__ __forceinline__ void compact_append(int flag, int ch, int lane,
                                               unsigned short* actrow, int* cntp)
{
    unsigned long long m = __ballot(flag);
    int base = 0;
    if (lane == 0 && m) base = atomicAdd(cntp, __popcll(m));
    base = __shfl(base, 0);
    if (flag) actrow[base + __popcll(m & ((1ull << lane) - 1ull))] = (unsigned short)ch;
}

__global__ __launch_bounds__(256) void ka_qkv(
    const float* __restrict__ x, float* __restrict__ ws,
    const float* __restrict__ qg, const float* __restrict__ qb,
    const float* __restrict__ qm, const float* __restrict__ qv,
    const float* __restrict__ kg, const float* __restrict__ kb,
    const float* __restrict__ km, const float* __restrict__ kvv,
    const float* __restrict__ vg, const float* __restrict__ vb,
    const float* __restrict__ vm, const float* __restrict__ vvv)
{
    const int n    = blockIdx.x;      // 0..195
    const int tid  = threadIdx.x;     // owns channels c0=2*tid, c1=2*tid+1
    const int lane = tid & 63;
    const int c0   = tid * 2;
    __shared__ unsigned short act[TT][CC];
    __shared__ int cnt[TT];
    if (tid < TT) cnt[tid] = 0;

    // --- shortcut LIF on x (local; depends only on this n) ---
    int xf0 = 0, xf1 = 0;
    {
        float v0 = 0.0f, v1 = 0.0f;
        const float* xp = x + (size_t)c0 * NN + n;
#pragma unroll
        for (int t = 0; t < TT; ++t) {
            const float a0 = xp[(size_t)t * CC * NN];
            const float a1 = xp[(size_t)t * CC * NN + NN];
            v0 = v0 + (a0 - v0) * 0.5f;
            v1 = v1 + (a1 - v1) * 0.5f;
            if (v0 >= 1.0f) { xf0 |= (1 << t); v0 = 0.0f; }
            if (v1 >= 1.0f) { xf1 |= (1 << t); v1 = 0.0f; }
        }
    }
    __syncthreads();   // cnt init visible
#pragma unroll
    for (int t = 0; t < TT; ++t) {
        compact_append((xf0 >> t) & 1, c0,     lane, act[t], &cnt[t]);
        compact_append((xf1 >> t) & 1, c0 + 1, lane, act[t], &cnt[t]);
    }
    __syncthreads();

    int ct[TT], mc = 0;
#pragma unroll
    for (int t = 0; t < TT; ++t) { ct[t] = cnt[t]; mc = max(mc, ct[t]); }

    // --- sparse accumulate, float2 (8B/lane coalesced), t-interleaved ---
    float aqx[TT] = {0,0,0,0}, aqy[TT] = {0,0,0,0};
    float akx[TT] = {0,0,0,0}, aky[TT] = {0,0,0,0};
    float avx[TT] = {0,0,0,0}, avy[TT] = {0,0,0,0};
    {
        const float2* Wq2 = (const float2*)(ws + WQT_OFF);
        const float2* Wk2 = (const float2*)(ws + WKT_OFF);
        const float2* Wv2 = (const float2*)(ws + WVT_OFF);
        for (int i = 0; i < mc; ++i) {
#pragma unroll
            for (int t = 0; t < TT; ++t) {
                if (i < ct[t]) {               // block-uniform, no divergence
                    const int c = act[t][i];   // LDS broadcast
                    const float2 wq = Wq2[c * 256 + tid];
                    const float2 wk = Wk2[c * 256 + tid];
                    const float2 wv = Wv2[c * 256 + tid];
                    aqx[t] += wq.x; aqy[t] += wq.y;
                    akx[t] += wk.x; aky[t] += wk.y;
                    avx[t] += wv.x; avy[t] += wv.y;
                }
            }
        }
    }

    // --- BN + LIF (v_th = 1) for channels c0, c0+1 ---
    int sqb0, sqb1, skb0, skb1, svb0, svb1;
    {
        float2 g = ((const float2*)qg)[tid], bta = ((const float2*)qb)[tid];
        float2 mn = ((const float2*)qm)[tid], vr = ((const float2*)qv)[tid];
        float sc = g.x / sqrtf(vr.x + BEPS);
        sqb0 = bn_lif4(aqx, sc, bta.x - mn.x * sc);
        sc = g.y / sqrtf(vr.y + BEPS);
        sqb1 = bn_lif4(aqy, sc, bta.y - mn.y * sc);
        g = ((const float2*)kg)[tid]; bta = ((const float2*)kb)[tid];
        mn = ((const float2*)km)[tid]; vr = ((const float2*)kvv)[tid];
        sc = g.x / sqrtf(vr.x + BEPS);
        skb0 = bn_lif4(akx, sc, bta.x - mn.x * sc);
        sc = g.y / sqrtf(vr.y + BEPS);
        skb1 = bn_lif4(aky, sc, bta.y - mn.y * sc);
        g = ((const float2*)vg)[tid]; bta = ((const float2*)vb)[tid];
        mn = ((const float2*)vm)[tid]; vr = ((const float2*)vvv)[tid];
        sc = g.x / sqrtf(vr.x + BEPS);
        svb0 = bn_lif4(avx, sc, bta.x - mn.x * sc);
        sc = g.y / sqrtf(vr.y + BEPS);
        svb1 = bn_lif4(avy, sc, bta.y - mn.y * sc);
    }

    // --- store sq bytes; accumulate kvsum[t][c] += sk & sv ---
    {
        uchar2 s; s.x = (unsigned char)sqb0; s.y = (unsigned char)sqb1;
        ((uchar2*)((unsigned char*)(ws + SQ_OFF)))[n * 256 + tid] = s;
    }
    {
        float* kvsum = ws + KV_OFF;
        const int b0 = skb0 & svb0, b1 = skb1 & svb1;
#pragma unroll
        for (int t = 0; t < TT; ++t) {
            if ((b0 >> t) & 1) atomicAdd(&kvsum[t * CC + c0], 1.0f);
            if ((b1 >> t) & 1) atomicAdd(&kvsum[t * CC + c0 + 1], 1.0f);
        }
    }
}

__global__ __launch_bounds__(256) void kb_proj(
    const float* __restrict__ x, const float* __restrict__ ws,
    const float* __restrict__ pbias,
    const float* __restrict__ pg, const float* __restrict__ pb,
    const float* __restrict__ pm, const float* __restrict__ pv,
    float* __restrict__ out)
{
    const int n    = blockIdx.x;
    const int tid  = threadIdx.x;       // channels c0=2*tid, c0+1
    const int lane = tid & 63;
    const int c0   = tid * 2;
    __shared__ unsigned short act[TT][CC];
    __shared__ int cnt[TT];
    if (tid < TT) cnt[tid] = 0;

    // talking-heads LIF (v_th = 0.5) on kvsum; AND with sq byte for this n
    int f0 = 0, f1 = 0;
    {
        const float2* kv2 = (const float2*)(ws + KV_OFF);
        const uchar2 s = ((const uchar2*)((const unsigned char*)(ws + SQ_OFF)))[n * 256 + tid];
        float v0 = 0.0f, v1 = 0.0f;
#pragma unroll
        for (int t = 0; t < TT; ++t) {
            const float2 a = kv2[t * 256 + tid];
            v0 = v0 + (a.x - v0) * 0.5f;
            v1 = v1 + (a.y - v1) * 0.5f;
            const int g0 = (v0 >= 0.5f), g1 = (v1 >= 0.5f);
            if (g0) v0 = 0.0f;
            if (g1) v1 = 0.0f;
            if (g0 && ((s.x >> t) & 1)) f0 |= (1 << t);
            if (g1 && ((s.y >> t) & 1)) f1 |= (1 << t);
        }
    }
    __syncthreads();
#pragma unroll
    for (int t = 0; t < TT; ++t) {
        compact_append((f0 >> t) & 1, c0,     lane, act[t], &cnt[t]);
        compact_append((f1 >> t) & 1, c0 + 1, lane, act[t], &cnt[t]);
    }
    __syncthreads();

    int ct[TT], mc = 0;
#pragma unroll
    for (int t = 0; t < TT; ++t) { ct[t] = cnt[t]; mc = max(mc, ct[t]); }

    float ax[TT] = {0,0,0,0}, ay[TT] = {0,0,0,0};
    {
        const float2* Wp2 = (const float2*)(ws + WPT_OFF);
        for (int i = 0; i < mc; ++i) {
#pragma unroll
            for (int t = 0; t < TT; ++t) {
                if (i < ct[t]) {
                    const int c = act[t][i];
                    const float2 w = Wp2[c * 256 + tid];
                    ax[t] += w.x; ay[t] += w.y;
                }
            }
        }
    }

    // epilogue: (acc + bias)*scale + offset + identity
    {
        const float2 g  = ((const float2*)pg)[tid];
        const float2 bt = ((const float2*)pb)[tid];
        const float2 mn = ((const float2*)pm)[tid];
        const float2 vr = ((const float2*)pv)[tid];
        const float2 bi = ((const float2*)pbias)[tid];
        const float sc0 = g.x / sqrtf(vr.x + BEPS);
        const float of0 = bt.x - mn.x * sc0;
        const float sc1 = g.y / sqrtf(vr.y + BEPS);
        const float of1 = bt.y - mn.y * sc1;
#pragma unroll
        for (int t = 0; t < TT; ++t) {
            const size_t i0 = (size_t)(t * CC + c0) * NN + n;
            out[i0]      = (ax[t] + bi.x) * sc0 + of0 + x[i0];
            out[i0 + NN] = (ay[t] + bi.y) * sc1 + of1 + x[i0 + NN];
        }
    }
}

extern "C" void kernel_launch(void* const* d_in, const int* in_sizes, int n_in,
                              void* d_out, int out_size, void* d_ws, size_t ws_size,
                              hipStream_t stream) {
    const float* x     = (const float*)d_in[0];
    const float* qw    = (const float*)d_in[1];
    const float* kw    = (const float*)d_in[2];
    const float* vw    = (const float*)d_in[3];
    const float* pw    = (const float*)d_in[4];
    const float* pbias = (const float*)d_in[5];
    const float* qg = (const float*)d_in[6],  *qb = (const float*)d_in[7];
    const float* qm = (const float*)d_in[8],  *qv = (const float*)d_in[9];
    const float* kg = (const float*)d_in[10], *kb = (const float*)d_in[11];
    const float* km = (const float*)d_in[12], *kv = (const float*)d_in[13];
    const float* vg = (const float*)d_in[14], *vb = (const float*)d_in[15];
    const float* vm = (const float*)d_in[16], *vv = (const float*)d_in[17];
    const float* pg = (const float*)d_in[18], *pb = (const float*)d_in[19];
    const float* pm = (const float*)d_in[20], *pv = (const float*)d_in[21];
    float* ws  = (float*)d_ws;
    float* out = (float*)d_out;

    hipLaunchKernelGGL(k0_prep, dim3(256), dim3(256), 0, stream, qw, kw, vw, pw, ws);
    hipLaunchKernelGGL(ka_qkv, dim3(196), dim3(256), 0, stream, x, ws,
                       qg, qb, qm, qv, kg, kb, km, kv, vg, vb, vm, vv);
    hipLaunchKernelGGL(kb_proj, dim3(196), dim3(256), 0, stream, x, ws,
                       pbias, pg, pb, pm, pv, out);
}